// Round 5
// baseline (298.976 us; speedup 1.0000x reference)
//
#include <hip/hip_runtime.h>
#include <math.h>

#define WIN 11
#define OH 32               // output rows per tile
#define OW 64               // output cols per tile
#define VSTRH 80            // vb row stride in HALFS (160B, 16B-aligned rows)
#define PLANEH (OH * VSTRH) // 2560 halfs per channel
#define IMG 512
#define OUTD 502            // 512 - 10 (VALID)
#define NIMG 64

typedef _Float16 half8v __attribute__((ext_vector_type(8)));
typedef _Float16 half4v __attribute__((ext_vector_type(4)));
typedef _Float16 half2v __attribute__((ext_vector_type(2)));

struct GW { float w[WIN]; };

__global__ __launch_bounds__(64) void ssim_zero(double* acc) {
    acc[0] = 0.0;
}

__global__ __launch_bounds__(256, 6) void ssim_kernel(
    const float* __restrict__ X, const float* __restrict__ Y,
    double* __restrict__ acc, GW gw)
{
    __shared__ _Float16 vb[5 * PLANEH];   // 25600 B -> 6 blocks/CU
    __shared__ float red[4];

    const int tid = threadIdx.x;
    const int tC = blockIdx.x, tR = blockIdx.y, b = blockIdx.z;
    const int gr0 = tR * OH, gc0 = tC * OW;
    const float* __restrict__ Xb = X + (size_t)b * (IMG * IMG);
    const float* __restrict__ Yb = Y + (size_t)b * (IMG * IMG);

    // ---- Phase B: vertical 11-tap conv of 5 derived channels, straight from
    // global (coalesced float4; L1/L2 serve the ~2.7x halo re-reads).
    // Task = 4 output rows x 4 cols. 8 row-groups x 19 col-groups = 152 tasks.
    if (tid < 152) {
        const int rg = tid / 19, cg = tid - rg * 19;
        const int r0 = rg * 4;
        int gc = gc0 + cg * 4;
        if (gc > IMG - 4) gc = IMG - 4;   // clamped cols only feed masked outputs

        float a[5][4][4] = {};
        #pragma unroll
        for (int k = 0; k < 4 + WIN - 1; ++k) {
            int gr = gr0 + r0 + k; if (gr > IMG - 1) gr = IMG - 1;
            const float4 xv = *reinterpret_cast<const float4*>(Xb + (size_t)gr * IMG + gc);
            const float4 yv = *reinterpret_cast<const float4*>(Yb + (size_t)gr * IMG + gc);
            float xs[4] = {xv.x, xv.y, xv.z, xv.w};
            float ys[4] = {yv.x, yv.y, yv.z, yv.w};
            float xx[4], yy[4], xy[4];
            #pragma unroll
            for (int c = 0; c < 4; ++c) {
                xx[c] = xs[c] * xs[c];
                yy[c] = ys[c] * ys[c];
                xy[c] = xs[c] * ys[c];
            }
            #pragma unroll
            for (int i2 = 0; i2 < 4; ++i2) {
                const int t = k - i2;
                if (t >= 0 && t < WIN) {     // compile-time after unroll
                    const float wt = gw.w[t];
                    #pragma unroll
                    for (int c = 0; c < 4; ++c) {
                        a[0][i2][c] += wt * xs[c];
                        a[1][i2][c] += wt * ys[c];
                        a[2][i2][c] += wt * xx[c];
                        a[3][i2][c] += wt * yy[c];
                        a[4][i2][c] += wt * xy[c];
                    }
                }
            }
        }
        #pragma unroll
        for (int ch = 0; ch < 5; ++ch) {
            #pragma unroll
            for (int i2 = 0; i2 < 4; ++i2) {
                half4v hv;
                hv.x = (_Float16)a[ch][i2][0];
                hv.y = (_Float16)a[ch][i2][1];
                hv.z = (_Float16)a[ch][i2][2];
                hv.w = (_Float16)a[ch][i2][3];
                *reinterpret_cast<half4v*>(&vb[ch * PLANEH + (r0 + i2) * VSTRH + cg * 4]) = hv;
            }
        }
    }
    __syncthreads();

    // ---- Phase C: horizontal 11-tap conv + SSIM, 8 outputs/thread ----
    const int r  = tid >> 3;          // 0..31
    const int c0 = (tid & 7) * 8;     // 0..56 (halfs; 16B-aligned reads)
    const _Float16* vrow = &vb[r * VSTRH + c0];

    float m[5][8];
    #pragma unroll
    for (int ch = 0; ch < 5; ++ch) {
        const _Float16* p = vrow + ch * PLANEH;
        half8v v0 = *reinterpret_cast<const half8v*>(p);
        half8v v1 = *reinterpret_cast<const half8v*>(p + 8);
        half2v v2 = *reinterpret_cast<const half2v*>(p + 16);
        float w18[18];
        #pragma unroll
        for (int j = 0; j < 8; ++j) w18[j] = (float)v0[j];
        #pragma unroll
        for (int j = 0; j < 8; ++j) w18[8 + j] = (float)v1[j];
        w18[16] = (float)v2.x;
        w18[17] = (float)v2.y;
        #pragma unroll
        for (int o = 0; o < 8; ++o) {
            float s = 0.f;
            #pragma unroll
            for (int t = 0; t < WIN; ++t) s += gw.w[t] * w18[o + t];
            m[ch][o] = s;
        }
    }

    const float C1 = 1e-4f, C2 = 9e-4f;
    float ssv[8];
    #pragma unroll
    for (int o = 0; o < 8; ++o) {
        float mu1 = m[0][o], mu2 = m[1][o];
        float mu1s = mu1 * mu1, mu2s = mu2 * mu2, m12 = mu1 * mu2;
        float s1  = m[2][o] - mu1s;
        float s2  = m[3][o] - mu2s;
        float s12 = m[4][o] - m12;
        float num = (2.f * s12 + C2) * (2.f * m12 + C1);
        float den = (s1 + s2 + C2) * (mu1s + mu2s + C1);
        ssv[o] = num * __builtin_amdgcn_rcpf(den);
    }

    float lsum = 0.f;
    if (tR < 15 && tC < 7) {               // interior tile: no masking needed
        #pragma unroll
        for (int o = 0; o < 8; ++o) lsum += ssv[o];
    } else {
        const int ogr = gr0 + r;
        #pragma unroll
        for (int o = 0; o < 8; ++o) {
            const int ogc = gc0 + c0 + o;
            if (ogr < OUTD && ogc < OUTD) lsum += ssv[o];
        }
    }

    // ---- block reduce -> one double atomic per block ----
    #pragma unroll
    for (int off = 32; off > 0; off >>= 1)
        lsum += __shfl_down(lsum, off, 64);
    if ((tid & 63) == 0) red[tid >> 6] = lsum;
    __syncthreads();
    if (tid == 0) {
        float bs = red[0] + red[1] + red[2] + red[3];
        atomicAdd(acc, (double)bs);
    }
}

__global__ void ssim_finalize(const double* __restrict__ acc,
                              float* __restrict__ out) {
    out[0] = 1.0f - (float)(acc[0] / (double)((long long)NIMG * OUTD * OUTD));
}

extern "C" void kernel_launch(void* const* d_in, const int* in_sizes, int n_in,
                              void* d_out, int out_size, void* d_ws, size_t ws_size,
                              hipStream_t stream) {
    const float* X = (const float*)d_in[0];
    const float* Y = (const float*)d_in[1];
    double* acc = (double*)d_ws;
    float* out = (float*)d_out;

    // Exact pytorch_msssim Gaussian window, computed in double on host.
    GW gw;
    double c[WIN], s = 0.0;
    for (int i = 0; i < WIN; ++i) {
        double d = (double)i - (double)(WIN / 2);
        c[i] = exp(-(d * d) / (2.0 * 1.5 * 1.5));
        s += c[i];
    }
    for (int i = 0; i < WIN; ++i) gw.w[i] = (float)(c[i] / s);

    ssim_zero<<<1, 64, 0, stream>>>(acc);
    dim3 grid(IMG / OW, IMG / OH, NIMG);   // (8, 16, 64)
    ssim_kernel<<<grid, 256, 0, stream>>>(X, Y, acc, gw);
    ssim_finalize<<<1, 1, 0, stream>>>(acc, out);
}

// Round 6
// 146.249 us; speedup vs baseline: 2.0443x; 2.0443x over previous
//
#include <hip/hip_runtime.h>
#include <math.h>

#define WIN 11
#define OH 32               // output rows per tile
#define OW 54               // output cols per tile
#define IWV 64              // vb cols = OW + 10 (exactly 64)
#define VSTRH 64            // vb row stride in halfs (128 B)
#define PLANEH (OH * VSTRH) // 2048 halfs per channel
#define IMG 512
#define OUTD 502            // 512 - 10 (VALID)
#define NIMG 64
#define NTX 10              // ceil(502 / 54)

typedef float    f32x2 __attribute__((ext_vector_type(2)));
typedef _Float16 h2    __attribute__((ext_vector_type(2)));
typedef _Float16 h8    __attribute__((ext_vector_type(8)));

struct GW {
    float    wf[WIN];    // f32 weights (phase B)
    unsigned whp[WIN];   // fp16 weight splatted into both halves (phase C pk ops)
};

__device__ inline h2 wsplat(unsigned u) {
    union { unsigned u; h2 h; } x; x.u = u; return x.h;
}

__global__ __launch_bounds__(64) void ssim_zero(double* acc) {
    if (threadIdx.x == 0) acc[0] = 0.0;
}

// Empirical model: __launch_bounds__(256, N) -> VGPR cap = 512/(2N).
// N=4 -> 64 VGPR -> 8 waves/SIMD; LDS 20480 B -> 8 blocks/CU.
__global__ __launch_bounds__(256, 4) void ssim_kernel(
    const float* __restrict__ X, const float* __restrict__ Y,
    double* __restrict__ acc, GW gw)
{
    __shared__ _Float16 vb[5 * PLANEH];   // 20480 B exactly
    __shared__ float red[4];

    const int tid = threadIdx.x;
    const int tC = blockIdx.x, tR = blockIdx.y, b = blockIdx.z;
    const int gr0 = tR * OH, gc0 = tC * OW;
    const float* __restrict__ Xb = X + (size_t)b * (IMG * IMG);
    const float* __restrict__ Yb = Y + (size_t)b * (IMG * IMG);

    // ---- Phase B: vertical 11-tap conv of 5 derived channels from global.
    // Exactly 256 tasks: 8 row-groups (4 rows) x 32 col-groups (2 cols).
    {
        const int rg = tid >> 5, cg = tid & 31;
        const int r0 = rg * 4;
        int gc = gc0 + cg * 2;
        if (gc > IMG - 2) gc = IMG - 2;   // clamped cols only feed masked outputs

        f32x2 a[5][4] = {};
        #pragma unroll
        for (int k = 0; k < 4 + WIN - 1; ++k) {
            int gr = gr0 + r0 + k; if (gr > IMG - 1) gr = IMG - 1;
            const float2 xv = *reinterpret_cast<const float2*>(Xb + (size_t)gr * IMG + gc);
            const float2 yv = *reinterpret_cast<const float2*>(Yb + (size_t)gr * IMG + gc);
            f32x2 x = {xv.x, xv.y};
            f32x2 y = {yv.x, yv.y};
            f32x2 xx = x * x, yy = y * y, xy = x * y;
            #pragma unroll
            for (int i2 = 0; i2 < 4; ++i2) {
                const int t = k - i2;
                if (t >= 0 && t < WIN) {          // compile-time after unroll
                    const float wt = gw.wf[t];
                    a[0][i2] += wt * x;
                    a[1][i2] += wt * y;
                    a[2][i2] += wt * xx;
                    a[3][i2] += wt * yy;
                    a[4][i2] += wt * xy;
                }
            }
        }
        #pragma unroll
        for (int ch = 0; ch < 5; ++ch) {
            #pragma unroll
            for (int i2 = 0; i2 < 4; ++i2) {
                h2 hv = { (_Float16)a[ch][i2].x, (_Float16)a[ch][i2].y };
                *reinterpret_cast<h2*>(&vb[ch * PLANEH + (r0 + i2) * VSTRH + cg * 2]) = hv;
            }
        }
    }
    __syncthreads();

    // ---- Phase C: horizontal 11-tap conv (packed fp16) + SSIM (f32).
    // 8 threads/row x 8 cols each over 64 vb cols; cols >= 54 masked.
    const int r   = tid >> 3;         // 0..31
    const int c0h = (tid & 7) * 8;    // 0..56 (halfs == cols)
    const _Float16* rb = &vb[r * VSTRH];

    // clamped read bases (garbage lands only in masked outputs)
    const int b1 = (c0h == 56) ? 56 : c0h + 8;
    int b2 = c0h + 16; if (b2 > 62) b2 = 62;

    h2 m[5][4];
    #pragma unroll
    for (int ch = 0; ch < 5; ++ch) {
        const _Float16* p = rb + ch * PLANEH;
        h8 v0 = *reinterpret_cast<const h8*>(p + c0h);
        h8 v1 = *reinterpret_cast<const h8*>(p + b1);
        h2 e8 = *reinterpret_cast<const h2*>(p + b2);
        h2 e[9];
        #pragma unroll
        for (int j = 0; j < 4; ++j) { e[j] = h2{ v0[2*j], v0[2*j+1] }; }
        #pragma unroll
        for (int j = 0; j < 4; ++j) { e[4+j] = h2{ v1[2*j], v1[2*j+1] }; }
        e[8] = e8;
        h2 o[8];
        #pragma unroll
        for (int j = 0; j < 8; ++j) { o[j] = h2{ e[j][1], e[j+1][0] }; }

        #pragma unroll
        for (int pr = 0; pr < 4; ++pr) {
            h2 s = h2{ (_Float16)0, (_Float16)0 };
            #pragma unroll
            for (int u = 0; u < 6; ++u)           // even taps 0,2,4,6,8,10
                s += wsplat(gw.whp[2*u]) * e[pr + u];
            #pragma unroll
            for (int u = 0; u < 5; ++u)           // odd taps 1,3,5,7,9
                s += wsplat(gw.whp[2*u+1]) * o[pr + u];
            m[ch][pr] = s;
        }
    }

    const float C1 = 1e-4f, C2 = 9e-4f;
    int cmax = OUTD - gc0; if (cmax > OW) cmax = OW;   // 54, or 16 on last col-tile
    const int rmax = OUTD - gr0;                        // >=32 except last row-tile
    const bool rowok = (r < rmax);

    float lsum = 0.f;
    #pragma unroll
    for (int pr = 0; pr < 4; ++pr) {
        #pragma unroll
        for (int h = 0; h < 2; ++h) {
            float mu1 = (float)m[0][pr][h];
            float mu2 = (float)m[1][pr][h];
            float mu1s = mu1 * mu1, mu2s = mu2 * mu2, m12 = mu1 * mu2;
            float s1  = (float)m[2][pr][h] - mu1s;
            float s2  = (float)m[3][pr][h] - mu2s;
            float s12 = (float)m[4][pr][h] - m12;
            float num = (2.f * s12 + C2) * (2.f * m12 + C1);
            float den = (s1 + s2 + C2) * (mu1s + mu2s + C1);
            float ss  = num * __builtin_amdgcn_rcpf(den);
            if (rowok && (c0h + 2*pr + h) < cmax) lsum += ss;
        }
    }

    // ---- block reduce -> one double atomic per block ----
    #pragma unroll
    for (int off = 32; off > 0; off >>= 1)
        lsum += __shfl_down(lsum, off, 64);
    if ((tid & 63) == 0) red[tid >> 6] = lsum;
    __syncthreads();
    if (tid == 0) {
        float bs = red[0] + red[1] + red[2] + red[3];
        atomicAdd(acc, (double)bs);
    }
}

__global__ void ssim_finalize(const double* __restrict__ acc,
                              float* __restrict__ out) {
    out[0] = 1.0f - (float)(acc[0] / (double)((long long)NIMG * OUTD * OUTD));
}

static unsigned short f2h_rne(float f) {
    union { float f; unsigned u; } v; v.f = f;
    unsigned u = v.u;
    unsigned s = (u >> 16) & 0x8000u;
    int e = (int)((u >> 23) & 0xff) - 112;      // biased-15 exponent
    unsigned mant = u & 0x7fffffu;
    unsigned h = s | ((unsigned)e << 10) | (mant >> 13);
    unsigned rem = mant & 0x1fffu;
    if (rem > 0x1000u || (rem == 0x1000u && (h & 1u))) h++;
    return (unsigned short)h;
}

extern "C" void kernel_launch(void* const* d_in, const int* in_sizes, int n_in,
                              void* d_out, int out_size, void* d_ws, size_t ws_size,
                              hipStream_t stream) {
    const float* X = (const float*)d_in[0];
    const float* Y = (const float*)d_in[1];
    double* acc = (double*)d_ws;
    float* out = (float*)d_out;

    // Exact pytorch_msssim Gaussian window, computed in double on host.
    GW gw;
    double c[WIN], s = 0.0;
    for (int i = 0; i < WIN; ++i) {
        double d = (double)i - (double)(WIN / 2);
        c[i] = exp(-(d * d) / (2.0 * 1.5 * 1.5));
        s += c[i];
    }
    for (int i = 0; i < WIN; ++i) {
        float w = (float)(c[i] / s);
        gw.wf[i] = w;
        unsigned short hb = f2h_rne(w);
        gw.whp[i] = (unsigned)hb | ((unsigned)hb << 16);
    }

    ssim_zero<<<1, 64, 0, stream>>>(acc);
    dim3 grid(NTX, IMG / OH, NIMG);   // (10, 16, 64)
    ssim_kernel<<<grid, 256, 0, stream>>>(X, Y, acc, gw);
    ssim_finalize<<<1, 1, 0, stream>>>(acc, out);
}

// Round 8
// 124.648 us; speedup vs baseline: 2.3986x; 1.1733x over previous
//
#include <hip/hip_runtime.h>
#include <math.h>

#define WIN 11
#define OH 32               // output rows per tile
#define OW 64               // output cols per tile
#define VSTRH 80            // vb row stride in HALFS (160 B, 16B-aligned rows)
#define PLANEH (OH * VSTRH) // 2560 halfs per channel
#define IMG 512
#define OUTD 502            // 512 - 10 (VALID)
#define NIMG 64

typedef _Float16 h2 __attribute__((ext_vector_type(2)));
typedef _Float16 h4 __attribute__((ext_vector_type(4)));
typedef _Float16 h8 __attribute__((ext_vector_type(8)));
typedef __fp16   fp16x2 __attribute__((ext_vector_type(2)));

struct GW { unsigned whp[WIN]; };   // fp16 weight splatted into both halves

union U32H2 { unsigned u; h2 h; fp16x2 f; };
__device__ inline h2 wsplat(unsigned u) { U32H2 x; x.u = u; return x.h; }
__device__ inline h2 alignh(h2 hi, h2 lo) {   // {lo[1], hi[0]}
    U32H2 a, b, r; a.h = lo; b.h = hi;
    r.u = (a.u >> 16) | (b.u << 16);
    return r.h;
}
__device__ inline h2 pkrtz(float a, float b) {
    U32H2 x; x.f = __builtin_amdgcn_cvt_pkrtz(a, b); return x.h;
}

__global__ __launch_bounds__(64) void ssim_zero(double* acc) {
    if (threadIdx.x == 0) acc[0] = 0.0;
}

// launch_bounds model (measured R3/R4/R5): (256,N) -> VGPR cap = 512/(2N).
// N=3 -> cap 85. LDS 25.6KB -> 6 blocks/CU; VGPR<=85 -> 6 waves/SIMD. 75% occ ceiling.
__global__ __launch_bounds__(256, 3) void ssim_kernel(
    const float* __restrict__ X, const float* __restrict__ Y,
    double* __restrict__ acc, GW gw)
{
    __shared__ _Float16 vb[5 * PLANEH];   // 25600 B
    __shared__ float red[4];

    const int tid = threadIdx.x;
    const int tC = blockIdx.x, tR = blockIdx.y, b = blockIdx.z;
    const int gr0 = tR * OH, gc0 = tC * OW;
    const float* __restrict__ Xb = X + (size_t)b * (IMG * IMG);
    const float* __restrict__ Yb = Y + (size_t)b * (IMG * IMG);

    // ---- Phase B: vertical 11-tap conv of 5 derived channels from global,
    // packed-fp16 accumulation. Task = 4 rows x 4 cols; 8 x 19 = 152 tasks.
    if (tid < 152) {
        const int rg = tid / 19, cg = tid - rg * 19;
        const int r0 = rg * 4;
        int gc = gc0 + cg * 4;
        if (gc > IMG - 4) gc = IMG - 4;   // clamped cols only feed masked outputs

        h2 a[5][4][2] = {};               // [ch][row][colpair]
        #pragma unroll
        for (int k = 0; k < 4 + WIN - 1; ++k) {
            int gr = gr0 + r0 + k; if (gr > IMG - 1) gr = IMG - 1;
            const float4 xv = *reinterpret_cast<const float4*>(Xb + (size_t)gr * IMG + gc);
            const float4 yv = *reinterpret_cast<const float4*>(Yb + (size_t)gr * IMG + gc);
            h2 x0 = pkrtz(xv.x, xv.y);
            h2 x1 = pkrtz(xv.z, xv.w);
            h2 y0 = pkrtz(yv.x, yv.y);
            h2 y1 = pkrtz(yv.z, yv.w);
            h2 xx0 = x0 * x0, xx1 = x1 * x1;
            h2 yy0 = y0 * y0, yy1 = y1 * y1;
            h2 xy0 = x0 * y0, xy1 = x1 * y1;
            #pragma unroll
            for (int i2 = 0; i2 < 4; ++i2) {
                const int t = k - i2;
                if (t >= 0 && t < WIN) {          // compile-time after unroll
                    const h2 wt = wsplat(gw.whp[t]);
                    a[0][i2][0] += wt * x0;  a[0][i2][1] += wt * x1;
                    a[1][i2][0] += wt * y0;  a[1][i2][1] += wt * y1;
                    a[2][i2][0] += wt * xx0; a[2][i2][1] += wt * xx1;
                    a[3][i2][0] += wt * yy0; a[3][i2][1] += wt * yy1;
                    a[4][i2][0] += wt * xy0; a[4][i2][1] += wt * xy1;
                }
            }
        }
        #pragma unroll
        for (int ch = 0; ch < 5; ++ch) {
            #pragma unroll
            for (int i2 = 0; i2 < 4; ++i2) {
                h4 v;
                v[0] = a[ch][i2][0][0]; v[1] = a[ch][i2][0][1];
                v[2] = a[ch][i2][1][0]; v[3] = a[ch][i2][1][1];
                *reinterpret_cast<h4*>(&vb[ch * PLANEH + (r0 + i2) * VSTRH + cg * 4]) = v;
            }
        }
    }
    __syncthreads();

    // ---- Phase C: horizontal 11-tap conv (packed fp16) + SSIM (f32).
    // 8 threads/row x 8 outputs each; 18-half window fits stride-80 rows, no clamps.
    const int r   = tid >> 3;         // 0..31
    const int c0h = (tid & 7) * 8;    // 0..56
    const _Float16* rb = &vb[r * VSTRH];

    h2 m[5][4];
    #pragma unroll
    for (int ch = 0; ch < 5; ++ch) {
        const _Float16* p = rb + ch * PLANEH;
        h8 v0 = *reinterpret_cast<const h8*>(p + c0h);
        h8 v1 = *reinterpret_cast<const h8*>(p + c0h + 8);
        h2 e8 = *reinterpret_cast<const h2*>(p + c0h + 16);
        h2 e[9];
        #pragma unroll
        for (int j = 0; j < 4; ++j) e[j]     = h2{ v0[2*j], v0[2*j+1] };
        #pragma unroll
        for (int j = 0; j < 4; ++j) e[4 + j] = h2{ v1[2*j], v1[2*j+1] };
        e[8] = e8;
        h2 o[8];
        #pragma unroll
        for (int j = 0; j < 8; ++j) o[j] = alignh(e[j+1], e[j]);

        #pragma unroll
        for (int pr = 0; pr < 4; ++pr) {
            h2 s = h2{ (_Float16)0, (_Float16)0 };
            #pragma unroll
            for (int u = 0; u < 6; ++u)           // even taps 0,2,4,6,8,10
                s += wsplat(gw.whp[2*u]) * e[pr + u];
            #pragma unroll
            for (int u = 0; u < 5; ++u)           // odd taps 1,3,5,7,9
                s += wsplat(gw.whp[2*u+1]) * o[pr + u];
            m[ch][pr] = s;
        }
    }

    const float C1 = 1e-4f, C2 = 9e-4f;
    float ssv[8];
    #pragma unroll
    for (int pr = 0; pr < 4; ++pr) {
        #pragma unroll
        for (int h = 0; h < 2; ++h) {
            float mu1 = (float)m[0][pr][h];
            float mu2 = (float)m[1][pr][h];
            float mu1s = mu1 * mu1, mu2s = mu2 * mu2, m12 = mu1 * mu2;
            float s1  = (float)m[2][pr][h] - mu1s;
            float s2  = (float)m[3][pr][h] - mu2s;
            float s12 = (float)m[4][pr][h] - m12;
            float num = (2.f * s12 + C2) * (2.f * m12 + C1);
            float den = (s1 + s2 + C2) * (mu1s + mu2s + C1);
            ssv[2*pr + h] = num * __builtin_amdgcn_rcpf(den);
        }
    }

    float lsum = 0.f;
    if (tR < 15 && tC < 7) {               // interior tile: no masking needed
        #pragma unroll
        for (int o = 0; o < 8; ++o) lsum += ssv[o];
    } else {
        const int ogr = gr0 + r;
        #pragma unroll
        for (int o = 0; o < 8; ++o) {
            const int ogc = gc0 + c0h + o;
            if (ogr < OUTD && ogc < OUTD) lsum += ssv[o];
        }
    }

    // ---- block reduce -> one double atomic per block ----
    #pragma unroll
    for (int off = 32; off > 0; off >>= 1)
        lsum += __shfl_down(lsum, off, 64);
    if ((tid & 63) == 0) red[tid >> 6] = lsum;
    __syncthreads();
    if (tid == 0) {
        float bs = red[0] + red[1] + red[2] + red[3];
        atomicAdd(acc, (double)bs);
    }
}

__global__ void ssim_finalize(const double* __restrict__ acc,
                              float* __restrict__ out) {
    out[0] = 1.0f - (float)(acc[0] / (double)((long long)NIMG * OUTD * OUTD));
}

static unsigned short f2h_rne(float f) {
    union { float f; unsigned u; } v; v.f = f;
    unsigned u = v.u;
    unsigned s = (u >> 16) & 0x8000u;
    int e = (int)((u >> 23) & 0xff) - 112;      // biased-15 exponent
    unsigned mant = u & 0x7fffffu;
    unsigned h = s | ((unsigned)e << 10) | (mant >> 13);
    unsigned rem = mant & 0x1fffu;
    if (rem > 0x1000u || (rem == 0x1000u && (h & 1u))) h++;
    return (unsigned short)h;
}

extern "C" void kernel_launch(void* const* d_in, const int* in_sizes, int n_in,
                              void* d_out, int out_size, void* d_ws, size_t ws_size,
                              hipStream_t stream) {
    const float* X = (const float*)d_in[0];
    const float* Y = (const float*)d_in[1];
    double* acc = (double*)d_ws;
    float* out = (float*)d_out;

    // Exact pytorch_msssim Gaussian window (double on host), rounded to fp16.
    GW gw;
    double c[WIN], s = 0.0;
    for (int i = 0; i < WIN; ++i) {
        double d = (double)i - (double)(WIN / 2);
        c[i] = exp(-(d * d) / (2.0 * 1.5 * 1.5));
        s += c[i];
    }
    for (int i = 0; i < WIN; ++i) {
        unsigned short hb = f2h_rne((float)(c[i] / s));
        gw.whp[i] = (unsigned)hb | ((unsigned)hb << 16);
    }

    ssim_zero<<<1, 64, 0, stream>>>(acc);
    dim3 grid(IMG / OW, IMG / OH, NIMG);   // (8, 16, 64)
    ssim_kernel<<<grid, 256, 0, stream>>>(X, Y, acc, gw);
    ssim_finalize<<<1, 1, 0, stream>>>(acc, out);
}